// Round 2
// baseline (1176.857 us; speedup 1.0000x reference)
//
#include <hip/hip_runtime.h>
#include <hip/hip_bf16.h>
#include <cstddef>

typedef unsigned short u16;
typedef unsigned int u32;
typedef short short8 __attribute__((ext_vector_type(8)));
typedef float floatx4 __attribute__((ext_vector_type(4)));

#define T_STEPS 500
#define BATCH 64
#define INDIM 440
#define INPAD 448
#define HID 1024
#define OUTDIM 1944
#define OUTPAD 2048
#define MROWS 32000  // T*B
#define INV_SQRT_BN 0.9999950000374997f  // 1/sqrt(1+1e-5)
#define CH 20        // scan chunk: 500 = 25*20

__device__ __forceinline__ u16 f2bf_rne(float f) {
  u32 u = __float_as_uint(f);
  u32 r = (u + 0x7FFFu + ((u >> 16) & 1u)) >> 16;
  return (u16)r;
}
__device__ __forceinline__ u16 f2bf_exact(float f) {
  return (u16)(__float_as_uint(f) >> 16);
}
__device__ __forceinline__ void g2lds16(const void* g, void* l) {
  __builtin_amdgcn_global_load_lds(
      (const __attribute__((address_space(1))) u32*)g,
      (__attribute__((address_space(3))) u32*)l, 16, 0, 0);
}

// ---------------- input FSQ scan: xs [T,B,440] -> spikes bf16 [T*B, 448] ----
__global__ __launch_bounds__(256) void input_fsq_k(const float* __restrict__ xs,
                                                   u16* __restrict__ sp0) {
  int tid = blockIdx.x * 256 + threadIdx.x;  // 64*448
  int b = tid / INPAD;
  int i = tid - b * INPAD;
  bool act = (i < INDIM);
  const float* src = xs + (size_t)b * INDIM + (act ? i : (INDIM - 1));
  u16* dst = sp0 + (size_t)b * INPAD + i;
  float fact = act ? 1.f : 0.f;
  const int LS = BATCH * INDIM;
  const int SS = BATCH * INPAD;
  float vmem = 0.f;
  float bufA[CH], bufB[CH];
#pragma unroll
  for (int j = 0; j < CH; ++j) bufA[j] = src[(size_t)j * LS];
  for (int it = 0; it < 12; ++it) {
    const int t0 = it * 2 * CH;
#pragma unroll
    for (int j = 0; j < CH; ++j) bufB[j] = src[(size_t)(t0 + CH + j) * LS];
#pragma unroll
    for (int j = 0; j < CH; ++j) {
      vmem += bufA[j] * fact;
      float q = fminf(fmaxf(rintf(vmem), 0.f), 7.f);
      vmem -= q;
      dst[(size_t)(t0 + j) * SS] = f2bf_exact(q);
    }
#pragma unroll
    for (int j = 0; j < CH; ++j) bufA[j] = src[(size_t)(t0 + 2 * CH + j) * LS];
#pragma unroll
    for (int j = 0; j < CH; ++j) {
      vmem += bufB[j] * fact;
      float q = fminf(fmaxf(rintf(vmem), 0.f), 7.f);
      vmem -= q;
      dst[(size_t)(t0 + CH + j) * SS] = f2bf_exact(q);
    }
  }
  const int t0 = 24 * CH;
#pragma unroll
  for (int j = 0; j < CH; ++j) {
    vmem += bufA[j] * fact;
    float q = fminf(fmaxf(rintf(vmem), 0.f), 7.f);
    vmem -= q;
    dst[(size_t)(t0 + j) * SS] = f2bf_exact(q);
  }
}

// ---------------- LIF scan: ws fp32 [T*B, 1024] -> spikes bf16 ----
__global__ __launch_bounds__(256) void lif_k(const float* __restrict__ ws,
                                             const float* __restrict__ taus,
                                             u16* __restrict__ sp) {
  int tid = blockIdx.x * 256 + threadIdx.x;  // 65536 = B*HID
  float tau = taus[tid & (HID - 1)];
  const float* src = ws + tid;
  u16* dst = sp + tid;
  const int S = BATCH * HID;
  float syn = 0.f, vmem = 0.f;
  float bufA[CH], bufB[CH];
#pragma unroll
  for (int j = 0; j < CH; ++j) bufA[j] = src[(size_t)j * S];
  for (int it = 0; it < 12; ++it) {
    const int t0 = it * 2 * CH;
#pragma unroll
    for (int j = 0; j < CH; ++j) bufB[j] = src[(size_t)(t0 + CH + j) * S];
#pragma unroll
    for (int j = 0; j < CH; ++j) {
      syn = fmaf(tau, syn, bufA[j]);
      vmem += syn;
      float q = fminf(fmaxf(rintf(vmem), 0.f), 7.f);
      vmem -= q;
      dst[(size_t)(t0 + j) * S] = f2bf_exact(q);
    }
#pragma unroll
    for (int j = 0; j < CH; ++j) bufA[j] = src[(size_t)(t0 + 2 * CH + j) * S];
#pragma unroll
    for (int j = 0; j < CH; ++j) {
      syn = fmaf(tau, syn, bufB[j]);
      vmem += syn;
      float q = fminf(fmaxf(rintf(vmem), 0.f), 7.f);
      vmem -= q;
      dst[(size_t)(t0 + CH + j) * S] = f2bf_exact(q);
    }
  }
  const int t0 = 24 * CH;
#pragma unroll
  for (int j = 0; j < CH; ++j) {
    syn = fmaf(tau, syn, bufA[j]);
    vmem += syn;
    float q = fminf(fmaxf(rintf(vmem), 0.f), 7.f);
    vmem -= q;
    dst[(size_t)(t0 + j) * S] = f2bf_exact(q);
  }
}

// ---------------- weight prep: fold BN gamma, split to bf16 hi/lo ----
__global__ __launch_bounds__(256) void prep_w0_k(const float* __restrict__ W0,
                                                 const float* __restrict__ g,
                                                 u16* __restrict__ hi, u16* __restrict__ lo) {
  int idx = blockIdx.x * 256 + threadIdx.x;  // 1024*448
  int h = idx / INPAD, k = idx - h * INPAD;
  float w = 0.f;
  if (k < INDIM) w = W0[(size_t)h * INDIM + k] * g[h] * INV_SQRT_BN;
  u16 hb = f2bf_rne(w);
  float hf = __uint_as_float((u32)hb << 16);
  hi[idx] = hb;
  lo[idx] = f2bf_rne(w - hf);
}
__global__ __launch_bounds__(256) void prep_ws_k(const float* __restrict__ Ws,
                                                 const float* __restrict__ g,
                                                 u16* __restrict__ hi, u16* __restrict__ lo) {
  int idx = blockIdx.x * 256 + threadIdx.x;  // 3*1024*1024
  int l = idx >> 20;
  int h = (idx >> 10) & (HID - 1);
  float w = Ws[idx] * g[(l + 1) * HID + h] * INV_SQRT_BN;
  u16 hb = f2bf_rne(w);
  float hf = __uint_as_float((u32)hb << 16);
  hi[idx] = hb;
  lo[idx] = f2bf_rne(w - hf);
}
__global__ __launch_bounds__(256) void prep_wf_k(const float* __restrict__ Wf,
                                                 const float* __restrict__ g,
                                                 u16* __restrict__ hi) {
  int idx = blockIdx.x * 256 + threadIdx.x;  // 2048*1024
  int o = idx >> 10, k = idx & (HID - 1);
  float w = 0.f;
  if (o < OUTDIM) w = Wf[(size_t)o * HID + k] * g[o] * INV_SQRT_BN;
  hi[idx] = f2bf_rne(w);
}

// ---------------- 256x256-tile 4-phase pipelined GEMM --------------------
// Schedule v2 (m201-faithful):
//  - phase p's ds_reads issued BEFORE its opening barrier (latency hides
//    under barrier skew + prior MFMA-pipe drain); lgkmcnt(0)+sched_barrier
//    after the barrier (rule #18).
//  - ALL 8 stage loads for tile t+1 issued as a burst in phase 1 of tile t
//    (order A0 A1 B0 B1 B2 B3 A2 A3) -> every block has >=3-phase lead.
//  - counted waits at phase ends (steady state): ph1-end vmcnt(10)
//    publishes B2,B3; ph2-end vmcnt(8) publishes A2,A3; ph4-end vmcnt(4)
//    publishes next tile's A0,A1,B0,B1.  Never 0 in the main loop.
//    Invariant: every ds_read of LDS region R is issued after a
//    {vmcnt retiring R's staging; s_barrier} pair.
//  - last tile peeled with waits 2/0/0, no staging.
// Geometry unchanged from v1: 512 thr = 8 waves (2M x 4N), per-wave 128x64,
// LDS 2x(A 256x64 + B 256x64) bf16 = 128 KiB, zero-conflict 16B-chunk XOR
// swizzle, permuted LDS row blocks (1 stage inst == 1 quadrant's data).

template <int SPLIT>
__global__ __launch_bounds__(512, 2) void gemm8(
    const u16* __restrict__ A, const u16* __restrict__ B0,
    const u16* __restrict__ B1, const float* __restrict__ bias,
    float* __restrict__ C, int K, int NT, int ldc, int ncols) {
  extern __shared__ char smem[];
  u16* const As = (u16*)smem;          // [2][256][64]
  u16* const Bs = As + 2 * 256 * 64;   // [2][256][64]

  const int tid = threadIdx.x;
  const int lane = tid & 63;
  const int wave = tid >> 6;
  const int wm = wave >> 2;   // 0..1
  const int wn = wave & 3;    // 0..3
  const int lr = lane & 15;
  const int lq = lane >> 4;

  const int m0 = blockIdx.y * 256;
  const int nb = blockIdx.x;

  // ---- staging source pointers (per stage-instruction q = 0..3)
  const int t3 = tid >> 3;                  // 0..63
  const int sj = (tid & 7) ^ (t3 & 7);      // swizzled source chunk
  const u16* aS[4];
  const u16* bS[4];
#pragma unroll
  for (int q = 0; q < 4; ++q) {
    int grow = ((q & 1) << 7) + ((q >> 1) << 6) + t3;  // A global row
    aS[q] = A + (size_t)(m0 + grow) * K + sj * 8;
    int cc = ((q >> 1) & 1) * 32 + ((tid >> 8) << 6) + (t3 & 31);
    if (SPLIT) {
      const u16* bp = (q & 1) ? B1 : B0;
      bS[q] = bp + (size_t)(nb * 128 + cc) * K + sj * 8;
    } else {
      bS[q] = B0 + (size_t)(nb * 256 + ((q & 1) << 7) + cc) * K + sj * 8;
    }
  }
  const int ldSt = tid * 16;  // byte offset within an 8KB stage block

#define STG_A(q_, koff_, buf_) \
  g2lds16(aS[q_] + (koff_), (char*)As + (buf_)*32768 + (q_)*8192 + ldSt)
#define STG_B(q_, koff_, buf_) \
  g2lds16(bS[q_] + (koff_), (char*)Bs + (buf_)*32768 + (q_)*8192 + ldSt)

  // ---- read-side addressing
  const int sw = lr & 7;
  const int co0 = ((lq ^ sw) << 3);        // kk=0: chunk jc = lq
  const int co1 = (((4 + lq) ^ sw) << 3);  // kk=1: chunk jc = 4+lq
  const int rA = wm * 64 + lr;             // + mq*128 + i*16
  const int rB = wn * 32 + lr;             // + nq*128 + jj*16

#define LDA(buf_, row_, co_) (*(const short8*)(As + (buf_)*16384 + (row_)*64 + (co_)))
#define LDB(buf_, row_, co_) (*(const short8*)(Bs + (buf_)*16384 + (row_)*64 + (co_)))

#define WAITVM(n_)                                            \
  do {                                                        \
    asm volatile("s_waitcnt vmcnt(" #n_ ")" ::: "memory");    \
    __builtin_amdgcn_sched_barrier(0);                        \
  } while (0)
#define BARRIER                                               \
  do {                                                        \
    __builtin_amdgcn_s_barrier();                             \
    __builtin_amdgcn_sched_barrier(0);                        \
  } while (0)
#define LGKM0                                                 \
  do {                                                        \
    asm volatile("s_waitcnt lgkmcnt(0)" ::: "memory");        \
    __builtin_amdgcn_sched_barrier(0);                        \
  } while (0)

  floatx4 acc[8][4];
#pragma unroll
  for (int i = 0; i < 8; ++i)
#pragma unroll
    for (int j = 0; j < 4; ++j) acc[i][j] = (floatx4){0.f, 0.f, 0.f, 0.f};

  short8 a0[4][2], a1[4][2], bf0[2][2], bf1[2][2];

#define MFMA16(aF, bF, i0_, j0_)                                            \
  do {                                                                      \
    __builtin_amdgcn_s_setprio(1);                                          \
    _Pragma("unroll") for (int kk = 0; kk < 2; ++kk)                        \
    _Pragma("unroll") for (int i = 0; i < 4; ++i)                           \
    _Pragma("unroll") for (int jj = 0; jj < 2; ++jj)                        \
      acc[(i0_) + i][(j0_) + jj] = __builtin_amdgcn_mfma_f32_16x16x32_bf16( \
          aF[i][kk], bF[jj][kk], acc[(i0_) + i][(j0_) + jj], 0, 0, 0);      \
    __builtin_amdgcn_s_setprio(0);                                          \
  } while (0)

#define TILE(cb_, ob_, kn_, V1_, V2_, V3_, STG_)                  \
  do {                                                            \
    /* ph1: (mq0,nq0) — reads pre-barrier; stage burst of 8 */    \
    _Pragma("unroll") for (int i = 0; i < 4; ++i) {               \
      a0[i][0] = LDA(cb_, i * 16 + rA, co0);                      \
      a0[i][1] = LDA(cb_, i * 16 + rA, co1);                      \
    }                                                             \
    _Pragma("unroll") for (int jj = 0; jj < 2; ++jj) {            \
      bf0[jj][0] = LDB(cb_, jj * 16 + rB, co0);                   \
      bf0[jj][1] = LDB(cb_, jj * 16 + rB, co1);                   \
    }                                                             \
    if (STG_) {                                                   \
      STG_A(0, kn_, ob_); STG_A(1, kn_, ob_);                     \
      STG_B(0, kn_, ob_); STG_B(1, kn_, ob_);                     \
      STG_B(2, kn_, ob_); STG_B(3, kn_, ob_);                     \
      STG_A(2, kn_, ob_); STG_A(3, kn_, ob_);                     \
    }                                                             \
    asm volatile("s_waitcnt lgkmcnt(8)" ::: "memory");            \
    BARRIER;                                                      \
    LGKM0;                                                        \
    MFMA16(a0, bf0, 0, 0);                                        \
    WAITVM(V1_);                                                  \
    BARRIER;                                                      \
    /* ph2: (mq0,nq1) */                                          \
    _Pragma("unroll") for (int jj = 0; jj < 2; ++jj) {            \
      bf1[jj][0] = LDB(cb_, 128 + jj * 16 + rB, co0);             \
      bf1[jj][1] = LDB(cb_, 128 + jj * 16 + rB, co1);             \
    }                                                             \
    BARRIER;                                                      \
    LGKM0;                                                        \
    MFMA16(a0, bf1, 0, 2);                                        \
    WAITVM(V2_);                                                  \
    BARRIER;                                                      \
    /* ph3: (mq1,nq1) */                                          \
    _Pragma("unroll") for (int i = 0; i < 4; ++i) {               \
      a1[i][0] = LDA(cb_, 128 + i * 16 + rA, co0);                \
      a1[i][1] = LDA(cb_, 128 + i * 16 + rA, co1);                \
    }                                                             \
    BARRIER;                                                      \
    LGKM0;                                                        \
    MFMA16(a1, bf1, 4, 2);                                        \
    BARRIER;                                                      \
    /* ph4: (mq1,nq0) — pure MFMA (a1, bf0 held) */               \
    MFMA16(a1, bf0, 4, 0);                                        \
    WAITVM(V3_);                                                  \
    BARRIER;                                                      \
  } while (0)

  // prologue: stage tile 0 into buf 0 (canonical L-order), publish A0A1B0B1
  STG_A(0, 0, 0); STG_A(1, 0, 0);
  STG_B(0, 0, 0); STG_B(1, 0, 0);
  STG_B(2, 0, 0); STG_B(3, 0, 0);
  STG_A(2, 0, 0); STG_A(3, 0, 0);
  WAITVM(4);
  BARRIER;

  for (int kt = 0; kt < NT - 1; ++kt) {
    const int cb = kt & 1;
    TILE(cb, cb ^ 1, (kt + 1) * 64, 10, 8, 4, 1);
  }
  {  // peeled last tile: no staging; drains remaining loads (2/0/0)
    const int cb = (NT - 1) & 1;
    TILE(cb, cb ^ 1, 0, 2, 0, 0, 0);
  }

  // ---- epilogue: slabs of 32 rows through LDS -> full-line float4 stores
  if (!SPLIT) {
    float* Es = (float*)smem;  // [32][260]
    const int n0 = nb * 256;
    float bv[4];
#pragma unroll
    for (int j = 0; j < 4; ++j) {
      int cg = n0 + wn * 64 + j * 16 + lr;
      bv[j] = (cg < ncols) ? bias[cg] : 0.f;
    }
#pragma unroll
    for (int s = 0; s < 8; ++s) {
      __syncthreads();
      if ((s >> 2) == wm) {
#pragma unroll
        for (int ii = 0; ii < 2; ++ii)
#pragma unroll
          for (int j = 0; j < 4; ++j) {
            floatx4 v = acc[(s & 3) * 2 + ii][j];
            int cl = wn * 64 + j * 16 + lr;
#pragma unroll
            for (int r = 0; r < 4; ++r)
              Es[(ii * 16 + lq * 4 + r) * 260 + cl] = v[r] + bv[j];
          }
      }
      __syncthreads();
#pragma unroll
      for (int p = 0; p < 4; ++p) {
        int fl = tid + p * 512;
        int row = fl >> 6, c4 = (fl & 63) << 2;
        int cg = n0 + c4;
        if (cg < ncols)
          *(floatx4*)(C + (size_t)(m0 + s * 32 + row) * ldc + cg) =
              *(const floatx4*)(Es + row * 260 + c4);
      }
    }
  } else {
    float* Es = (float*)smem;  // [32][132]
    const int n0 = nb * 128;
    float bv[4];
#pragma unroll
    for (int j = 0; j < 4; ++j)
      bv[j] = bias[n0 + (wn & 1) * 64 + j * 16 + lr];
#pragma unroll
    for (int s = 0; s < 8; ++s) {
      __syncthreads();
      if ((s >> 2) == wm && wn >= 2) {  // lo-partial waves write
#pragma unroll
        for (int ii = 0; ii < 2; ++ii)
#pragma unroll
          for (int j = 0; j < 4; ++j) {
            floatx4 v = acc[(s & 3) * 2 + ii][j];
            int cl = (wn - 2) * 64 + j * 16 + lr;
#pragma unroll
            for (int r = 0; r < 4; ++r)
              Es[(ii * 16 + lq * 4 + r) * 132 + cl] = v[r];
          }
      }
      __syncthreads();
      if ((s >> 2) == wm && wn < 2) {  // hi-partial waves accumulate + bias
#pragma unroll
        for (int ii = 0; ii < 2; ++ii)
#pragma unroll
          for (int j = 0; j < 4; ++j) {
            floatx4 v = acc[(s & 3) * 2 + ii][j];
            int cl = wn * 64 + j * 16 + lr;
#pragma unroll
            for (int r = 0; r < 4; ++r) {
              int e = (ii * 16 + lq * 4 + r) * 132 + cl;
              Es[e] = Es[e] + v[r] + bv[j];
            }
          }
      }
      __syncthreads();
#pragma unroll
      for (int p = 0; p < 2; ++p) {
        int fl = tid + p * 512;
        int row = fl >> 5, c4 = (fl & 31) << 2;
        *(floatx4*)(C + (size_t)(m0 + s * 32 + row) * ldc + n0 + c4) =
            *(const floatx4*)(Es + row * 132 + c4);
      }
    }
  }
#undef STG_A
#undef STG_B
#undef LDA
#undef LDB
#undef WAITVM
#undef BARRIER
#undef LGKM0
#undef MFMA16
#undef TILE
}

// ---------------- in-place log_softmax over rows of 1944 ----
__global__ __launch_bounds__(256) void logsoftmax_k(float* __restrict__ data) {
  __shared__ float red[8];
  float* p = data + (size_t)blockIdx.x * OUTDIM;
  const int t = threadIdx.x;
  float v[8];
  float mx = -1e30f;
#pragma unroll
  for (int j = 0; j < 8; ++j) {
    int c = t + j * 256;
    v[j] = (c < OUTDIM) ? p[c] : -1e30f;
    mx = fmaxf(mx, v[j]);
  }
#pragma unroll
  for (int o = 32; o > 0; o >>= 1) mx = fmaxf(mx, __shfl_down(mx, o));
  if ((t & 63) == 0) red[t >> 6] = mx;
  __syncthreads();
  mx = fmaxf(fmaxf(red[0], red[1]), fmaxf(red[2], red[3]));
  float s = 0.f;
#pragma unroll
  for (int j = 0; j < 8; ++j) {
    int c = t + j * 256;
    if (c < OUTDIM) s += __expf(v[j] - mx);
  }
#pragma unroll
  for (int o = 32; o > 0; o >>= 1) s += __shfl_down(s, o);
  if ((t & 63) == 0) red[4 + (t >> 6)] = s;
  __syncthreads();
  s = (red[4] + red[5]) + (red[6] + red[7]);
  float lse = mx + __logf(s);
#pragma unroll
  for (int j = 0; j < 8; ++j) {
    int c = t + j * 256;
    if (c < OUTDIM) p[c] = v[j] - lse;
  }
}

extern "C" void kernel_launch(void* const* d_in, const int* in_sizes, int n_in,
                              void* d_out, int out_size, void* d_ws, size_t ws_size,
                              hipStream_t stream) {
  const float* xs = (const float*)d_in[0];
  const float* W0 = (const float*)d_in[1];
  const float* Ws = (const float*)d_in[2];
  const float* taus = (const float*)d_in[3];
  const float* bng = (const float*)d_in[4];
  const float* bnb = (const float*)d_in[5];
  const float* Wf = (const float*)d_in[6];
  const float* fg = (const float*)d_in[7];
  const float* fb = (const float*)d_in[8];
  float* out = (float*)d_out;

  char* p = (char*)d_ws;
  u16* sp0 = (u16*)p;  p += (size_t)MROWS * INPAD * 2;
  u16* sp = (u16*)p;   p += (size_t)MROWS * HID * 2;
  float* wsb = (float*)p; p += (size_t)MROWS * HID * 4;
  u16* W0hi = (u16*)p; p += (size_t)HID * INPAD * 2;
  u16* W0lo = (u16*)p; p += (size_t)HID * INPAD * 2;
  u16* Whi = (u16*)p;  p += (size_t)3 * HID * HID * 2;
  u16* Wlo = (u16*)p;  p += (size_t)3 * HID * HID * 2;
  u16* Wfhi = (u16*)p; p += (size_t)OUTPAD * HID * 2;

  static int attr_done = 0;
  if (!attr_done) {
    hipFuncSetAttribute((const void*)gemm8<1>,
                        hipFuncAttributeMaxDynamicSharedMemorySize, 131072);
    hipFuncSetAttribute((const void*)gemm8<0>,
                        hipFuncAttributeMaxDynamicSharedMemorySize, 131072);
    attr_done = 1;
  }

  input_fsq_k<<<(BATCH * INPAD) / 256, 256, 0, stream>>>(xs, sp0);
  prep_w0_k<<<(HID * INPAD) / 256, 256, 0, stream>>>(W0, bng, W0hi, W0lo);
  prep_ws_k<<<(3 * HID * HID) / 256, 256, 0, stream>>>(Ws, bng, Whi, Wlo);
  prep_wf_k<<<(OUTPAD * HID) / 256, 256, 0, stream>>>(Wf, fg, Wfhi);

  // layer 0 (K = 448, NT = 7)
  gemm8<1><<<dim3(HID / 128, MROWS / 256), 512, 131072, stream>>>(
      sp0, W0hi, W0lo, bnb, wsb, INPAD, INPAD / 64, HID, HID);
  lif_k<<<(BATCH * HID) / 256, 256, 0, stream>>>(wsb, taus, sp);
  // layers 1..3 (K = 1024, NT = 16)
  for (int l = 1; l < 4; ++l) {
    gemm8<1><<<dim3(HID / 128, MROWS / 256), 512, 131072, stream>>>(
        sp, Whi + (size_t)(l - 1) * HID * HID, Wlo + (size_t)(l - 1) * HID * HID,
        bnb + l * HID, wsb, HID, HID / 64, HID, HID);
    lif_k<<<(BATCH * HID) / 256, 256, 0, stream>>>(wsb, taus + l * HID, sp);
  }
  // final projection -> d_out (raw logits), then in-place log_softmax
  gemm8<0><<<dim3(OUTPAD / 256, MROWS / 256), 512, 131072, stream>>>(
      sp, Wfhi, (const u16*)nullptr, fb, out, HID, HID / 64, OUTDIM, OUTDIM);
  logsoftmax_k<<<MROWS, 256, 0, stream>>>(out);
}

// Round 3
// 947.862 us; speedup vs baseline: 1.2416x; 1.2416x over previous
//
#include <hip/hip_runtime.h>
#include <hip/hip_bf16.h>
#include <cstddef>

typedef signed char i8;
typedef unsigned int u32;
typedef int intx4 __attribute__((ext_vector_type(4)));
typedef float floatx4 __attribute__((ext_vector_type(4)));

#define T_STEPS 500
#define BATCH 64
#define INDIM 440
#define INPAD 512   // i8 K-pad for layer-0 GEMM (BK=128)
#define HID 1024
#define OUTDIM 1944
#define OUTPAD 2048
#define MROWS 32000  // T*B
#define INV_SQRT_BN 0.9999950000374997f  // 1/sqrt(1+1e-5)
#define CH 20        // scan chunk: 500 = 25*20

__device__ __forceinline__ void g2lds16(const void* g, void* l) {
  __builtin_amdgcn_global_load_lds(
      (const __attribute__((address_space(1))) u32*)g,
      (__attribute__((address_space(3))) u32*)l, 16, 0, 0);
}

// ---------------- input FSQ scan: xs [T,B,440] -> spikes i8 [T*B, 512] ----
__global__ __launch_bounds__(256) void input_fsq_k(const float* __restrict__ xs,
                                                   i8* __restrict__ sp0) {
  int tid = blockIdx.x * 256 + threadIdx.x;  // 64*512
  int b = tid >> 9;
  int i = tid & 511;
  bool act = (i < INDIM);
  const float* src = xs + (size_t)b * INDIM + (act ? i : (INDIM - 1));
  i8* dst = sp0 + (size_t)b * INPAD + i;
  float fact = act ? 1.f : 0.f;
  const int LS = BATCH * INDIM;
  const int SS = BATCH * INPAD;
  float vmem = 0.f;
  float bufA[CH], bufB[CH];
#pragma unroll
  for (int j = 0; j < CH; ++j) bufA[j] = src[(size_t)j * LS];
  for (int it = 0; it < 12; ++it) {
    const int t0 = it * 2 * CH;
#pragma unroll
    for (int j = 0; j < CH; ++j) bufB[j] = src[(size_t)(t0 + CH + j) * LS];
#pragma unroll
    for (int j = 0; j < CH; ++j) {
      vmem += bufA[j] * fact;
      float q = fminf(fmaxf(rintf(vmem), 0.f), 7.f);
      vmem -= q;
      dst[(size_t)(t0 + j) * SS] = (i8)q;
    }
#pragma unroll
    for (int j = 0; j < CH; ++j) bufA[j] = src[(size_t)(t0 + 2 * CH + j) * LS];
#pragma unroll
    for (int j = 0; j < CH; ++j) {
      vmem += bufB[j] * fact;
      float q = fminf(fmaxf(rintf(vmem), 0.f), 7.f);
      vmem -= q;
      dst[(size_t)(t0 + CH + j) * SS] = (i8)q;
    }
  }
  const int t0 = 24 * CH;
#pragma unroll
  for (int j = 0; j < CH; ++j) {
    vmem += bufA[j] * fact;
    float q = fminf(fmaxf(rintf(vmem), 0.f), 7.f);
    vmem -= q;
    dst[(size_t)(t0 + j) * SS] = (i8)q;
  }
}

// ---------------- LIF scan: ws fp32 [T*B, 1024] -> spikes i8 ----
__global__ __launch_bounds__(256) void lif_k(const float* __restrict__ ws,
                                             const float* __restrict__ taus,
                                             i8* __restrict__ sp) {
  int tid = blockIdx.x * 256 + threadIdx.x;  // 65536 = B*HID
  float tau = taus[tid & (HID - 1)];
  const float* src = ws + tid;
  i8* dst = sp + tid;
  const int S = BATCH * HID;
  float syn = 0.f, vmem = 0.f;
  float bufA[CH], bufB[CH];
#pragma unroll
  for (int j = 0; j < CH; ++j) bufA[j] = src[(size_t)j * S];
  for (int it = 0; it < 12; ++it) {
    const int t0 = it * 2 * CH;
#pragma unroll
    for (int j = 0; j < CH; ++j) bufB[j] = src[(size_t)(t0 + CH + j) * S];
#pragma unroll
    for (int j = 0; j < CH; ++j) {
      syn = fmaf(tau, syn, bufA[j]);
      vmem += syn;
      float q = fminf(fmaxf(rintf(vmem), 0.f), 7.f);
      vmem -= q;
      dst[(size_t)(t0 + j) * S] = (i8)q;
    }
#pragma unroll
    for (int j = 0; j < CH; ++j) bufA[j] = src[(size_t)(t0 + 2 * CH + j) * S];
#pragma unroll
    for (int j = 0; j < CH; ++j) {
      syn = fmaf(tau, syn, bufB[j]);
      vmem += syn;
      float q = fminf(fmaxf(rintf(vmem), 0.f), 7.f);
      vmem -= q;
      dst[(size_t)(t0 + CH + j) * S] = (i8)q;
    }
  }
  const int t0 = 24 * CH;
#pragma unroll
  for (int j = 0; j < CH; ++j) {
    syn = fmaf(tau, syn, bufA[j]);
    vmem += syn;
    float q = fminf(fmaxf(rintf(vmem), 0.f), 7.f);
    vmem -= q;
    dst[(size_t)(t0 + j) * S] = (i8)q;
  }
}

// ---------------- weight prep: fold BN gamma, dual int8 row-quant ----
// w ≈ s1*q1 + s2*q2, per output row: s1 = max|w|/127, s2 = max|w-s1*q1|/127.
// Residual ≤ s2/2 ≈ max|w|/32k per element; i32 dots are EXACT.
// One wave per row; grid covers padded rows (pad rows -> q=0, s=1).
__global__ __launch_bounds__(256) void quant_rows_k(
    const float* __restrict__ W, const float* __restrict__ g,
    i8* __restrict__ Q1, i8* __restrict__ Q2,
    float* __restrict__ S1, float* __restrict__ S2,
    int K_in, int K_out, int nvalid) {
  int row = blockIdx.x * 4 + (threadIdx.x >> 6);
  int lane = threadIdx.x & 63;
  bool valid = row < nvalid;
  float gm = valid ? g[row] * INV_SQRT_BN : 0.f;
  const float* src = W + (size_t)row * K_in;
  float w[16], r[16];
  const int ne = K_out >> 6;  // 8 or 16
  float mx = 0.f;
  for (int e = 0; e < ne; ++e) {
    int k = lane + (e << 6);
    float v = (valid && k < K_in) ? src[k] * gm : 0.f;
    w[e] = v;
    mx = fmaxf(mx, fabsf(v));
  }
#pragma unroll
  for (int o = 32; o; o >>= 1) mx = fmaxf(mx, __shfl_xor(mx, o));
  float s1 = (mx > 0.f) ? mx * (1.f / 127.f) : 1.f;
  float inv1 = 1.f / s1;
  float mr = 0.f;
  for (int e = 0; e < ne; ++e) {
    float q = fminf(fmaxf(rintf(w[e] * inv1), -127.f), 127.f);
    Q1[(size_t)row * K_out + lane + (e << 6)] = (i8)q;
    float res = fmaf(-s1, q, w[e]);
    r[e] = res;
    mr = fmaxf(mr, fabsf(res));
  }
#pragma unroll
  for (int o = 32; o; o >>= 1) mr = fmaxf(mr, __shfl_xor(mr, o));
  float s2 = (mr > 0.f) ? mr * (1.f / 127.f) : 1.f;
  float inv2 = 1.f / s2;
  for (int e = 0; e < ne; ++e) {
    float q = fminf(fmaxf(rintf(r[e] * inv2), -127.f), 127.f);
    Q2[(size_t)row * K_out + lane + (e << 6)] = (i8)q;
  }
  if (lane == 0) {
    S1[row] = s1;
    S2[row] = s2;
  }
}

// ---------------- GEMM: C[m,n] = s1[n]*(A.q1[n]) + s2[n]*(A.q2[n]) + bias[n]
// i8 dual-matrix, BK=128 (bytes/row = 128 => byte-identical LDS layout and
// zero-conflict 16B-chunk XOR swizzle to the verified bf16 kernel).
// 128x128 tile, 4 waves (2x2 quadrants of 64x64), 48 KiB LDS, 2 blocks/CU.
// mfma_i32_16x16x64_i8: lane holds 16 consecutive k (16B) per operand.
__global__ __launch_bounds__(256, 2) void gemm_i8(
    const i8* __restrict__ A, const i8* __restrict__ B1q,
    const i8* __restrict__ B2q, const float* __restrict__ S1,
    const float* __restrict__ S2, const float* __restrict__ bias,
    float* __restrict__ C, int K, int ldc, int ncols) {
  extern __shared__ char smem[];
  char* As = smem;                 // [128][128] i8, swizzled 16B chunks
  char* Bs1 = As + 128 * 128;
  char* Bs2 = Bs1 + 128 * 128;

  const int tid = threadIdx.x;
  const int m0 = blockIdx.y * 128;
  const int n0 = blockIdx.x * 128;
  const int lane = tid & 63;
  const int wave = tid >> 6;
  const int wm = (wave & 1) * 64;
  const int wn = (wave >> 1) * 64;
  const int lr = lane & 15;
  const int lq = lane >> 4;  // 0..3

  intx4 acc1[4][4], acc2[4][4];
#pragma unroll
  for (int i = 0; i < 4; ++i)
#pragma unroll
    for (int j = 0; j < 4; ++j) {
      intx4 z = {0, 0, 0, 0};
      acc1[i][j] = z;
      acc2[i][j] = z;
    }

  const int srow = tid >> 3;                    // 0..31
  const int sj = (tid & 7) ^ (srow & 7);        // swizzled global 16B chunk
  const i8* ga = A + (size_t)(m0 + srow) * K + sj * 16;
  const i8* gb1 = B1q + (size_t)(n0 + srow) * K + sj * 16;
  const i8* gb2 = B2q + (size_t)(n0 + srow) * K + sj * 16;
  const int ldso = tid * 16;
  const int sw = lr & 7;                        // row-dependent XOR for reads

  for (int k0 = 0; k0 < K; k0 += 128) {
#pragma unroll
    for (int it = 0; it < 4; ++it) {
      g2lds16(ga + (size_t)(it * 32) * K + k0, As + ldso + it * 4096);
      g2lds16(gb1 + (size_t)(it * 32) * K + k0, Bs1 + ldso + it * 4096);
      g2lds16(gb2 + (size_t)(it * 32) * K + k0, Bs2 + ldso + it * 4096);
    }
    __syncthreads();
#pragma unroll
    for (int kk = 0; kk < 2; ++kk) {
      const int jc = kk * 4 + lq;               // global 16B k-chunk 0..7
      const int co = ((jc ^ sw) << 4);          // swizzled byte offset
      intx4 af[4];
#pragma unroll
      for (int i = 0; i < 4; ++i)
        af[i] = *(const intx4*)(As + (wm + i * 16 + lr) * 128 + co);
#pragma unroll
      for (int j = 0; j < 4; ++j) {
        const int bo = (wn + j * 16 + lr) * 128 + co;
        intx4 b1 = *(const intx4*)(Bs1 + bo);
#pragma unroll
        for (int i = 0; i < 4; ++i)
          acc1[i][j] = __builtin_amdgcn_mfma_i32_16x16x64_i8(af[i], b1, acc1[i][j], 0, 0, 0);
        intx4 b2 = *(const intx4*)(Bs2 + bo);
#pragma unroll
        for (int i = 0; i < 4; ++i)
          acc2[i][j] = __builtin_amdgcn_mfma_i32_16x16x64_i8(af[i], b2, acc2[i][j], 0, 0, 0);
      }
    }
    __syncthreads();
  }

  // ---- epilogue: scale-combine, 4 slabs of 32x128 via LDS, float4 stores
  float* Es = (float*)smem;        // [32][132] padded
  const int rq = lq * 4;
  const int rbase = (wave & 1) * 16;
  float s1v[4], s2v[4], bv[4];
#pragma unroll
  for (int j = 0; j < 4; ++j) {
    int cg = n0 + wn + j * 16 + lr;
    s1v[j] = S1[cg];  // S arrays allocated padded -> always in bounds
    s2v[j] = S2[cg];
    bv[j] = (cg < ncols) ? bias[cg] : 0.f;
  }
#pragma unroll
  for (int i = 0; i < 4; ++i) {
    __syncthreads();
#pragma unroll
    for (int j = 0; j < 4; ++j) {
      int cl = wn + j * 16 + lr;
#pragma unroll
      for (int r = 0; r < 4; ++r)
        Es[(rbase + rq + r) * 132 + cl] =
            fmaf(s1v[j], (float)acc1[i][j][r],
                 fmaf(s2v[j], (float)acc2[i][j][r], bv[j]));
    }
    __syncthreads();
#pragma unroll
    for (int ps = 0; ps < 4; ++ps) {
      int rl = ps * 8 + (tid >> 5);            // 0..31
      int c4 = (tid & 31) * 4;
      floatx4 v = *(const floatx4*)(Es + rl * 132 + c4);
      int rg = m0 + (rl >> 4) * 64 + i * 16 + (rl & 15);
      int cg = n0 + c4;
      if (cg < ncols)
        *(floatx4*)(C + (size_t)rg * ldc + cg) = v;
    }
  }
}

// ---------------- in-place log_softmax over rows of 1944 ----
__global__ __launch_bounds__(256) void logsoftmax_k(float* __restrict__ data) {
  __shared__ float red[8];
  float* p = data + (size_t)blockIdx.x * OUTDIM;
  const int t = threadIdx.x;
  float v[8];
  float mx = -1e30f;
#pragma unroll
  for (int j = 0; j < 8; ++j) {
    int c = t + j * 256;
    v[j] = (c < OUTDIM) ? p[c] : -1e30f;
    mx = fmaxf(mx, v[j]);
  }
#pragma unroll
  for (int o = 32; o > 0; o >>= 1) mx = fmaxf(mx, __shfl_down(mx, o));
  if ((t & 63) == 0) red[t >> 6] = mx;
  __syncthreads();
  mx = fmaxf(fmaxf(red[0], red[1]), fmaxf(red[2], red[3]));
  float s = 0.f;
#pragma unroll
  for (int j = 0; j < 8; ++j) {
    int c = t + j * 256;
    if (c < OUTDIM) s += __expf(v[j] - mx);
  }
#pragma unroll
  for (int o = 32; o > 0; o >>= 1) s += __shfl_down(s, o);
  if ((t & 63) == 0) red[4 + (t >> 6)] = s;
  __syncthreads();
  s = (red[4] + red[5]) + (red[6] + red[7]);
  float lse = mx + __logf(s);
#pragma unroll
  for (int j = 0; j < 8; ++j) {
    int c = t + j * 256;
    if (c < OUTDIM) p[c] = v[j] - lse;
  }
}

extern "C" void kernel_launch(void* const* d_in, const int* in_sizes, int n_in,
                              void* d_out, int out_size, void* d_ws, size_t ws_size,
                              hipStream_t stream) {
  const float* xs = (const float*)d_in[0];
  const float* W0 = (const float*)d_in[1];
  const float* Ws = (const float*)d_in[2];
  const float* taus = (const float*)d_in[3];
  const float* bng = (const float*)d_in[4];
  const float* bnb = (const float*)d_in[5];
  const float* Wf = (const float*)d_in[6];
  const float* fg = (const float*)d_in[7];
  const float* fb = (const float*)d_in[8];
  float* out = (float*)d_out;

  char* p = (char*)d_ws;
  i8* sp0 = (i8*)p;    p += (size_t)MROWS * INPAD;          // 16.4 MB
  i8* sp = (i8*)p;     p += (size_t)MROWS * HID;            // 32.8 MB
  float* wsb = (float*)p; p += (size_t)MROWS * HID * 4;     // 131 MB
  i8* Q1_0 = (i8*)p;   p += (size_t)HID * INPAD;
  i8* Q2_0 = (i8*)p;   p += (size_t)HID * INPAD;
  i8* Q1_l = (i8*)p;   p += (size_t)3 * HID * HID;
  i8* Q2_l = (i8*)p;   p += (size_t)3 * HID * HID;
  i8* Q1_f = (i8*)p;   p += (size_t)OUTPAD * HID;
  i8* Q2_f = (i8*)p;   p += (size_t)OUTPAD * HID;
  float* S1_0 = (float*)p; p += HID * 4;
  float* S2_0 = (float*)p; p += HID * 4;
  float* S1_l = (float*)p; p += 3 * HID * 4;
  float* S2_l = (float*)p; p += 3 * HID * 4;
  float* S1_f = (float*)p; p += OUTPAD * 4;
  float* S2_f = (float*)p; p += OUTPAD * 4;

  input_fsq_k<<<(BATCH * INPAD) / 256, 256, 0, stream>>>(xs, sp0);
  quant_rows_k<<<HID / 4, 256, 0, stream>>>(W0, bng, Q1_0, Q2_0, S1_0, S2_0,
                                            INDIM, INPAD, HID);
  for (int l = 1; l < 4; ++l)
    quant_rows_k<<<HID / 4, 256, 0, stream>>>(
        Ws + (size_t)(l - 1) * HID * HID, bng + l * HID,
        Q1_l + (size_t)(l - 1) * HID * HID, Q2_l + (size_t)(l - 1) * HID * HID,
        S1_l + (l - 1) * HID, S2_l + (l - 1) * HID, HID, HID, HID);
  quant_rows_k<<<OUTPAD / 4, 256, 0, stream>>>(Wf, fg, Q1_f, Q2_f, S1_f, S2_f,
                                               HID, HID, OUTDIM);

  // layer 0 (K = 512)
  gemm_i8<<<dim3(HID / 128, MROWS / 128), 256, 48 * 1024, stream>>>(
      sp0, Q1_0, Q2_0, S1_0, S2_0, bnb, wsb, INPAD, HID, HID);
  lif_k<<<(BATCH * HID) / 256, 256, 0, stream>>>(wsb, taus, sp);
  // layers 1..3 (K = 1024)
  for (int l = 1; l < 4; ++l) {
    gemm_i8<<<dim3(HID / 128, MROWS / 128), 256, 48 * 1024, stream>>>(
        sp, Q1_l + (size_t)(l - 1) * HID * HID, Q2_l + (size_t)(l - 1) * HID * HID,
        S1_l + (l - 1) * HID, S2_l + (l - 1) * HID, bnb + l * HID, wsb,
        HID, HID, HID);
    lif_k<<<(BATCH * HID) / 256, 256, 0, stream>>>(wsb, taus + l * HID, sp);
  }
  // final projection -> d_out (raw logits), then in-place log_softmax
  gemm_i8<<<dim3(OUTPAD / 128, MROWS / 128), 256, 48 * 1024, stream>>>(
      sp, Q1_f, Q2_f, S1_f, S2_f, fb, out, HID, OUTDIM, OUTDIM);
  logsoftmax_k<<<MROWS, 256, 0, stream>>>(out);
}